// Round 9
// baseline (391.056 us; speedup 1.0000x reference)
//
#include <hip/hip_runtime.h>

constexpr int B  = 8,  P = 50, N = 128, M = 128;
constexpr int EMB = 128, H = 8, D = 16;
constexpr int NE = 8;
constexpr int HD = H * D;        // 128
constexpr int E1 = EMB + 1;      // 129
constexpr int BP = B * P;        // 400
constexpr int T  = BP * N;       // 51200 tokens

// ---------------------------------------------------------------------------
// K1: q/k/v projections (r7-proven) + FOLDED prep at blockIdx.y==3.
// grid (400, 4), block 256. prep also zeroes bpdone[] (r19 fusion ticket).
// ---------------------------------------------------------------------------
__global__ __launch_bounds__(256) void proj_kernel(
    const float* __restrict__ nodes,  // [T][128]
    const float* __restrict__ routes, // [T][129]
    const float* __restrict__ Wq, const float* __restrict__ Wk,
    const float* __restrict__ Wv,
    float* __restrict__ qo, float* __restrict__ ko, float* __restrict__ vo,
    const float* __restrict__ We, const float* __restrict__ be,
    const float* __restrict__ Wf,
    float* __restrict__ Wep, float* __restrict__ bpv,
    float* __restrict__ importance, unsigned* __restrict__ ticket,
    unsigned* __restrict__ bpdone) {
    const int mat = blockIdx.y;

    if (mat == 3) {                   // ---- folded prep ----
        const int e = blockIdx.x;
        if (e >= NE) return;
        const int f = threadIdx.x;
        if (f < HD) {
            float a = 0.f;
            const long base = ((long)e * HD + f) * E1;
            for (int o = 0; o < E1; ++o) a += We[base + o] * Wf[o];
            Wep[e * HD + f] = a;
        } else if (f == HD) {
            float b = 0.f;
            for (int o = 0; o < E1; ++o) b += be[(long)e * E1 + o] * Wf[o];
            bpv[e] = b;
        }
        if (e == 0) {
            if (f >= 140 && f < 140 + NE) importance[f - 140] = 0.f;
            if (f == 150) *ticket = 0u;
        }
        if (e == 1) {                 // zero the per-bp completion counters
            bpdone[f] = 0u;
            if (f < BP - 256) bpdone[f + 256] = 0u;
        }
        return;
    }

    const float* __restrict__ X = (mat == 0) ? nodes : routes;
    const float* __restrict__ W = (mat == 0) ? Wq : (mat == 1 ? Wk : Wv);
    float* __restrict__ out     = (mat == 0) ? qo : (mat == 1 ? ko : vo);
    const int Kd = (mat == 0) ? EMB : E1;
    const int nit = (Kd + 7) >> 3;

    const int row0 = blockIdx.x * 128;
    const int tid  = threadIdx.x;
    const int tr   = tid >> 4;        // 0..15
    const int tc   = tid & 15;        // 0..15

    __shared__ float XT[2][8][132];   // [buf][k][row], padded
    __shared__ float WS[2][8][132];   // [buf][k][col]

    float acc[8][8];
    #pragma unroll
    for (int i = 0; i < 8; ++i)
        #pragma unroll
        for (int j = 0; j < 8; ++j) acc[i][j] = 0.f;

    float xr[4];
    float4 wr;
    const int xkx = tid & 7, xrr = tid >> 3;          // +i*32 rows
    const int wkx = tid >> 5, wc4 = (tid & 31) * 4;

    {   // prologue: fetch tile 0
        #pragma unroll
        for (int i = 0; i < 4; ++i) {
            int kg = xkx;
            xr[i] = (kg < Kd) ? X[(long)(row0 + xrr + i * 32) * Kd + kg] : 0.f;
        }
        wr = (wkx < Kd) ? *(const float4*)&W[(long)wkx * HD + wc4]
                        : make_float4(0.f, 0.f, 0.f, 0.f);
        #pragma unroll
        for (int i = 0; i < 4; ++i) XT[0][xkx][xrr + i * 32] = xr[i];
        *(float4*)&WS[0][wkx][wc4] = wr;
    }
    __syncthreads();

    for (int it = 0; it < nit; ++it) {
        const int buf = it & 1;
        if (it + 1 < nit) {
            const int kk = (it + 1) * 8;
            #pragma unroll
            for (int i = 0; i < 4; ++i) {
                int kg = kk + xkx;
                xr[i] = (kg < Kd) ? X[(long)(row0 + xrr + i * 32) * Kd + kg] : 0.f;
            }
            int kg = kk + wkx;
            wr = (kg < Kd) ? *(const float4*)&W[(long)kg * HD + wc4]
                           : make_float4(0.f, 0.f, 0.f, 0.f);
        }

        #pragma unroll
        for (int k = 0; k < 8; ++k) {
            float4 xa = *(const float4*)&XT[buf][k][tr * 4];
            float4 xb = *(const float4*)&XT[buf][k][64 + tr * 4];
            float4 wa = *(const float4*)&WS[buf][k][tc * 4];
            float4 wb = *(const float4*)&WS[buf][k][64 + tc * 4];
            float xv[8] = {xa.x, xa.y, xa.z, xa.w, xb.x, xb.y, xb.z, xb.w};
            float wvv[8] = {wa.x, wa.y, wa.z, wa.w, wb.x, wb.y, wb.z, wb.w};
            #pragma unroll
            for (int i = 0; i < 8; ++i)
                #pragma unroll
                for (int j = 0; j < 8; ++j) acc[i][j] += xv[i] * wvv[j];
        }

        if (it + 1 < nit) {
            const int nb = buf ^ 1;
            #pragma unroll
            for (int i = 0; i < 4; ++i) XT[nb][xkx][xrr + i * 32] = xr[i];
            *(float4*)&WS[nb][wkx][wc4] = wr;
        }
        __syncthreads();
    }

    #pragma unroll
    for (int i = 0; i < 8; ++i) {
        int r = row0 + (i < 4 ? 0 : 64) + tr * 4 + (i & 3);
        float4 o0 = make_float4(acc[i][0], acc[i][1], acc[i][2], acc[i][3]);
        float4 o1 = make_float4(acc[i][4], acc[i][5], acc[i][6], acc[i][7]);
        *(float4*)&out[(long)r * HD + tc * 4]      = o0;
        *(float4*)&out[(long)r * HD + 64 + tc * 4] = o1;
    }
}

// ---------------------------------------------------------------------------
// K2: attn (r0-frozen body, transposed stores) + FUSED moe (r19).
// grid (BP, 8), block 64 (1 wave). After xcatT stores each block bumps
// bpdone[bp] (release fence); the 8th finisher acquires, reuses kh's LDS
// (union) and runs moe for this bp with 64 threads = 2 tokens/thread.
// Reduction mapping is bit-identical to the 128-thread tree (pair-combine
// = the off=64 step). moe logic = r6 two-pass version (xreg regressed in
// r8, reverted). Loss via global ticket (r16-proven). Guards: VGPR <= ~84,
// WRITE ~25.8 MB (r7 spill signature is the failure mode to watch).
// ---------------------------------------------------------------------------
__global__ __launch_bounds__(64) void attn_moe_kernel(
    const float* __restrict__ qbuf,   // [T][128]
    const float* __restrict__ kbuf,   // [T][128]
    const float* __restrict__ vbuf,   // [T][128]
    const float* __restrict__ rmask,  // [BP*N][M]
    const float* __restrict__ ninf,   // [BP*N]
    const float* __restrict__ Wg,     // [128][8]
    const float* __restrict__ Wep,    // [8][128]
    const float* __restrict__ bpv,    // [8]
    float* __restrict__ importance,
    unsigned* __restrict__ bpdone,
    unsigned* __restrict__ ticket,
    float* __restrict__ xcatT,        // [BP][HD][N]
    float* __restrict__ out) {
    const int bp  = blockIdx.x;
    const int h   = blockIdx.y;
    const int tid = threadIdx.x;

    __shared__ union ShU {
        float kh[M][D];               // 8 KB, attn phase
        struct {                      // 8.6 KB, moe phase (kh dead)
            float Wg[EMB][NE];        // 4 KB
            float We[NE][132];        // padded
            float red[64];
            float imp[NE];
        } moe;
    } sh;

    // stage k: 512 float4s over 8 iterations (fills ALL 128 rows)
    #pragma unroll
    for (int i = 0; i < 8; ++i) {
        int e = tid + i * 64;         // f4 index 0..511
        int r = e >> 2, c4 = (e & 3) * 4;
        *(float4*)&sh.kh[r][c4] =
            *(const float4*)&kbuf[((long)bp * M + r) * HD + h * D + c4];
    }
    __syncthreads();

    const long t0 = (long)bp * N + tid, t1 = t0 + 64;

    // q rows, 1/sqrt(D)=0.25 folded in
    float qr0[16], qr1[16];
    {
        const float4* q0 = (const float4*)&qbuf[t0 * HD + h * D];
        const float4* q1 = (const float4*)&qbuf[t1 * HD + h * D];
        #pragma unroll
        for (int i = 0; i < 4; ++i) {
            float4 a = q0[i], b = q1[i];
            qr0[i*4+0] = a.x*0.25f; qr0[i*4+1] = a.y*0.25f;
            qr0[i*4+2] = a.z*0.25f; qr0[i*4+3] = a.w*0.25f;
            qr1[i*4+0] = b.x*0.25f; qr1[i*4+1] = b.y*0.25f;
            qr1[i*4+2] = b.z*0.25f; qr1[i*4+3] = b.w*0.25f;
        }
    }

    const float* __restrict__ vbase = vbuf + ((long)bp * M) * HD + h * D;
    const float4* rm0 = (const float4*)&rmask[t0 * M];
    const float4* rm1 = (const float4*)&rmask[t1 * M];

    float sum0 = 0.f, sum1 = 0.f;
    float o0[16], o1[16];
    #pragma unroll
    for (int d = 0; d < 16; ++d) { o0[d] = 0.f; o1[d] = 0.f; }

    for (int mb = 0; mb < 32; ++mb) {          // NOT force-unrolled (VGPR!)
        float4 r0 = rm0[mb], r1 = rm1[mb];
        float r0v[4] = {r0.x, r0.y, r0.z, r0.w};
        float r1v[4] = {r1.x, r1.y, r1.z, r1.w};
        #pragma unroll
        for (int j = 0; j < 4; ++j) {
            const int m = mb * 4 + j;
            const float4* k4 = (const float4*)&sh.kh[m][0];
            const float4* v4 = (const float4*)&vbase[(long)m * HD];  // wave-uniform
            float s0 = 0.f, s1 = 0.f;
            #pragma unroll
            for (int q4 = 0; q4 < 4; ++q4) {
                float4 kq = k4[q4];
                s0 += qr0[q4*4+0]*kq.x + qr0[q4*4+1]*kq.y
                    + qr0[q4*4+2]*kq.z + qr0[q4*4+3]*kq.w;
                s1 += qr1[q4*4+0]*kq.x + qr1[q4*4+1]*kq.y
                    + qr1[q4*4+2]*kq.z + qr1[q4*4+3]*kq.w;
            }
            float e0 = __expf(s0 + r0v[j]);
            float e1 = __expf(s1 + r1v[j]);
            sum0 += e0; sum1 += e1;
            #pragma unroll
            for (int q4 = 0; q4 < 4; ++q4) {
                float4 vq = v4[q4];
                o0[q4*4+0] += e0*vq.x; o0[q4*4+1] += e0*vq.y;
                o0[q4*4+2] += e0*vq.z; o0[q4*4+3] += e0*vq.w;
                o1[q4*4+0] += e1*vq.x; o1[q4*4+1] += e1*vq.y;
                o1[q4*4+2] += e1*vq.z; o1[q4*4+3] += e1*vq.w;
            }
        }
    }

    const float inv0 = ((ninf[t0] == 0.f) ? 1.f : 0.f) / sum0;
    const float inv1 = ((ninf[t1] == 0.f) ? 1.f : 0.f) / sum1;
    // transposed, lane-coalesced stores: xcatT[bp][h*16+d][n]
    float* __restrict__ xb = xcatT + (long)bp * HD * N + (long)h * D * N;
    #pragma unroll
    for (int d = 0; d < 16; ++d) {
        xb[d * N + tid]      = o0[d] * inv0;
        xb[d * N + tid + 64] = o1[d] * inv1;
    }

    // ---- per-bp completion ticket: 8th finisher runs moe for this bp ----
    __syncthreads();                  // all lanes' stores issued
    unsigned done = 0;
    if (tid == 0) {
        __threadfence();              // release xcatT stores
        done = atomicAdd(&bpdone[bp], 1u);
    }
    done = __shfl(done, 0);           // wave broadcast
    if (done != H - 1) return;

    __threadfence();                  // acquire other heads' xcatT stores
    __syncthreads();                  // kh dead -> LDS reuse safe

    // stage Wg (256 f4) and We' (256 f4) with 64 threads
    #pragma unroll
    for (int i = 0; i < 4; ++i) {
        int e4 = tid + i * 64;
        int r = e4 >> 1, c4 = (e4 & 1) * 4;
        *(float4*)&sh.moe.Wg[r][c4] = *(const float4*)&Wg[(long)r * NE + c4];
    }
    #pragma unroll
    for (int i = 0; i < 4; ++i) {
        int idx = tid + i * 64;
        int r = idx >> 5, c = (idx & 31) * 4;
        *(float4*)&sh.moe.We[r][c] = *(const float4*)&Wep[(long)r * HD + c];
    }
    if (tid < NE) sh.moe.imp[tid] = 0.f;
    __syncthreads();

    const float* __restrict__ xT = xcatT + (long)bp * HD * N;  // [f][n]
    float sv[2];
    #pragma unroll
    for (int half = 0; half < 2; ++half) {
        const int tok = tid + half * 64;
        float gl[NE];
        #pragma unroll
        for (int e = 0; e < NE; ++e) gl[e] = 0.f;
        for (int f = 0; f < HD; ++f) {       // f ascending: same sum order
            float xv = xT[f * N + tok];      // coalesced across lanes
            #pragma unroll
            for (int e = 0; e < NE; ++e) gl[e] += xv * sh.moe.Wg[f][e];
        }
        int e0 = 0; float v0 = gl[0];
        #pragma unroll
        for (int e = 1; e < NE; ++e) if (gl[e] > v0) { v0 = gl[e]; e0 = e; }
        int e1 = -1; float v1 = -3.4e38f;
        #pragma unroll
        for (int e = 0; e < NE; ++e) if (e != e0 && gl[e] > v1) { v1 = gl[e]; e1 = e; }
        float ex = __expf(v1 - v0);
        float g0 = 1.f / (1.f + ex);
        float g1 = ex / (1.f + ex);

        atomicAdd(&sh.moe.imp[e0], g0);
        atomicAdd(&sh.moe.imp[e1], g1);

        float s = g0 * bpv[e0] + g1 * bpv[e1];
        for (int f = 0; f < HD; ++f) {       // f ascending: same sum order
            float xv = xT[f * N + tok];      // L2-hot re-read (r6-proven)
            s += xv * (g0 * sh.moe.We[e0][f] + g1 * sh.moe.We[e1][f]);
        }
        sv[half] = 10.f * tanhf(s) + ninf[(long)bp * N + tok];
    }

    // softmax over n: pair-combine = off=64 step of the 128-thread tree
    sh.moe.red[tid] = fmaxf(sv[0], sv[1]);
    __syncthreads();
    for (int off = 32; off > 0; off >>= 1) {
        if (tid < off) sh.moe.red[tid] = fmaxf(sh.moe.red[tid], sh.moe.red[tid + off]);
        __syncthreads();
    }
    float mx = sh.moe.red[0];
    __syncthreads();
    float eA = __expf(sv[0] - mx);
    float eB = __expf(sv[1] - mx);
    sh.moe.red[tid] = eA + eB;
    __syncthreads();
    for (int off = 32; off > 0; off >>= 1) {
        if (tid < off) sh.moe.red[tid] += sh.moe.red[tid + off];
        __syncthreads();
    }
    float sum = sh.moe.red[0];

    out[(long)bp * N + tid]      = eA / sum;
    out[(long)bp * N + tid + 64] = eB / sum;

    __syncthreads();
    if (tid < NE) atomicAdd(&importance[tid], sh.moe.imp[tid]);

    // ---- fused moe_loss: last bp to finish computes it (r16-proven) ----
    __syncthreads();
    if (tid == 0) {
        __threadfence();
        unsigned tk = atomicAdd(ticket, 1u);
        if (tk == BP - 1) {
            __threadfence();
            float imp[NE];
            #pragma unroll
            for (int ei = 0; ei < NE; ++ei)
                imp[ei] = atomicAdd(&importance[ei], 0.f);  // coherent read
            float mean = 0.f;
            #pragma unroll
            for (int ei = 0; ei < NE; ++ei) mean += imp[ei];
            mean *= (1.f / NE);
            float var = 0.f;
            #pragma unroll
            for (int ei = 0; ei < NE; ++ei) {
                float d = imp[ei] - mean;
                var += d * d;
            }
            var *= (1.f / NE);
            out[T] = var / (mean * mean + 1e-10f);
        }
    }
}

// ---------------------------------------------------------------------------
extern "C" void kernel_launch(void* const* d_in, const int* in_sizes, int n_in,
                              void* d_out, int out_size, void* d_ws, size_t ws_size,
                              hipStream_t stream) {
    const float* nodes  = (const float*)d_in[0];
    const float* routes = (const float*)d_in[1];
    const float* ninf   = (const float*)d_in[2];
    const float* rmask  = (const float*)d_in[3];
    const float* Wq     = (const float*)d_in[4];
    const float* Wk     = (const float*)d_in[5];
    const float* Wv     = (const float*)d_in[6];
    const float* Wg     = (const float*)d_in[7];
    const float* We     = (const float*)d_in[8];
    const float* be     = (const float*)d_in[9];
    const float* Wfin   = (const float*)d_in[10];

    float* ws = (float*)d_ws;
    float* Wep        = ws + 16;
    float* bpv        = ws + 1040;
    float* importance = ws + 1048;
    unsigned* ticket  = (unsigned*)(ws + 1056);
    unsigned* bpdone  = (unsigned*)(ws + 2048);   // [BP]
    float* qbuf       = ws + 4096;
    float* kbuf       = qbuf + (long)T * HD;
    float* vbuf       = kbuf + (long)T * HD;
    float* xcatT      = vbuf + (long)T * HD;      // [BP][HD][N]

    float* out = (float*)d_out;

    proj_kernel<<<dim3(400, 4), 256, 0, stream>>>(nodes, routes, Wq, Wk, Wv,
                                                  qbuf, kbuf, vbuf,
                                                  We, be, Wfin, Wep, bpv,
                                                  importance, ticket, bpdone);
    attn_moe_kernel<<<dim3(BP, H), 64, 0, stream>>>(qbuf, kbuf, vbuf,
                                                    rmask, ninf,
                                                    Wg, Wep, bpv,
                                                    importance, bpdone, ticket,
                                                    xcatT, out);
}

// Round 10
// 353.354 us; speedup vs baseline: 1.1067x; 1.1067x over previous
//
#include <hip/hip_runtime.h>

constexpr int B  = 8,  P = 50, N = 128, M = 128;
constexpr int EMB = 128, H = 8, D = 16;
constexpr int NE = 8;
constexpr int HD = H * D;        // 128
constexpr int E1 = EMB + 1;      // 129
constexpr int BP = B * P;        // 400
constexpr int T  = BP * N;       // 51200 tokens

// ---------------------------------------------------------------------------
// K1: q/k/v projections (r7-proven) + FOLDED prep at blockIdx.y==3.
// grid (400, 4), block 256. (r17-proven; untouched)
// ---------------------------------------------------------------------------
__global__ __launch_bounds__(256) void proj_kernel(
    const float* __restrict__ nodes,  // [T][128]
    const float* __restrict__ routes, // [T][129]
    const float* __restrict__ Wq, const float* __restrict__ Wk,
    const float* __restrict__ Wv,
    float* __restrict__ qo, float* __restrict__ ko, float* __restrict__ vo,
    const float* __restrict__ We, const float* __restrict__ be,
    const float* __restrict__ Wf,
    float* __restrict__ Wep, float* __restrict__ bpv,
    float* __restrict__ importance, unsigned* __restrict__ ticket) {
    const int mat = blockIdx.y;

    if (mat == 3) {                   // ---- folded prep ----
        const int e = blockIdx.x;
        if (e >= NE) return;
        const int f = threadIdx.x;
        if (f < HD) {
            float a = 0.f;
            const long base = ((long)e * HD + f) * E1;
            for (int o = 0; o < E1; ++o) a += We[base + o] * Wf[o];
            Wep[e * HD + f] = a;
        } else if (f == HD) {
            float b = 0.f;
            for (int o = 0; o < E1; ++o) b += be[(long)e * E1 + o] * Wf[o];
            bpv[e] = b;
        }
        if (e == 0) {
            if (f >= 140 && f < 140 + NE) importance[f - 140] = 0.f;
            if (f == 150) *ticket = 0u;
        }
        return;
    }

    const float* __restrict__ X = (mat == 0) ? nodes : routes;
    const float* __restrict__ W = (mat == 0) ? Wq : (mat == 1 ? Wk : Wv);
    float* __restrict__ out     = (mat == 0) ? qo : (mat == 1 ? ko : vo);
    const int Kd = (mat == 0) ? EMB : E1;
    const int nit = (Kd + 7) >> 3;

    const int row0 = blockIdx.x * 128;
    const int tid  = threadIdx.x;
    const int tr   = tid >> 4;        // 0..15
    const int tc   = tid & 15;        // 0..15

    __shared__ float XT[2][8][132];   // [buf][k][row], padded
    __shared__ float WS[2][8][132];   // [buf][k][col]

    float acc[8][8];
    #pragma unroll
    for (int i = 0; i < 8; ++i)
        #pragma unroll
        for (int j = 0; j < 8; ++j) acc[i][j] = 0.f;

    float xr[4];
    float4 wr;
    const int xkx = tid & 7, xrr = tid >> 3;          // +i*32 rows
    const int wkx = tid >> 5, wc4 = (tid & 31) * 4;

    {   // prologue: fetch tile 0
        #pragma unroll
        for (int i = 0; i < 4; ++i) {
            int kg = xkx;
            xr[i] = (kg < Kd) ? X[(long)(row0 + xrr + i * 32) * Kd + kg] : 0.f;
        }
        wr = (wkx < Kd) ? *(const float4*)&W[(long)wkx * HD + wc4]
                        : make_float4(0.f, 0.f, 0.f, 0.f);
        #pragma unroll
        for (int i = 0; i < 4; ++i) XT[0][xkx][xrr + i * 32] = xr[i];
        *(float4*)&WS[0][wkx][wc4] = wr;
    }
    __syncthreads();

    for (int it = 0; it < nit; ++it) {
        const int buf = it & 1;
        if (it + 1 < nit) {
            const int kk = (it + 1) * 8;
            #pragma unroll
            for (int i = 0; i < 4; ++i) {
                int kg = kk + xkx;
                xr[i] = (kg < Kd) ? X[(long)(row0 + xrr + i * 32) * Kd + kg] : 0.f;
            }
            int kg = kk + wkx;
            wr = (kg < Kd) ? *(const float4*)&W[(long)kg * HD + wc4]
                           : make_float4(0.f, 0.f, 0.f, 0.f);
        }

        #pragma unroll
        for (int k = 0; k < 8; ++k) {
            float4 xa = *(const float4*)&XT[buf][k][tr * 4];
            float4 xb = *(const float4*)&XT[buf][k][64 + tr * 4];
            float4 wa = *(const float4*)&WS[buf][k][tc * 4];
            float4 wb = *(const float4*)&WS[buf][k][64 + tc * 4];
            float xv[8] = {xa.x, xa.y, xa.z, xa.w, xb.x, xb.y, xb.z, xb.w};
            float wvv[8] = {wa.x, wa.y, wa.z, wa.w, wb.x, wb.y, wb.z, wb.w};
            #pragma unroll
            for (int i = 0; i < 8; ++i)
                #pragma unroll
                for (int j = 0; j < 8; ++j) acc[i][j] += xv[i] * wvv[j];
        }

        if (it + 1 < nit) {
            const int nb = buf ^ 1;
            #pragma unroll
            for (int i = 0; i < 4; ++i) XT[nb][xkx][xrr + i * 32] = xr[i];
            *(float4*)&WS[nb][wkx][wc4] = wr;
        }
        __syncthreads();
    }

    #pragma unroll
    for (int i = 0; i < 8; ++i) {
        int r = row0 + (i < 4 ? 0 : 64) + tr * 4 + (i & 3);
        float4 o0 = make_float4(acc[i][0], acc[i][1], acc[i][2], acc[i][3]);
        float4 o1 = make_float4(acc[i][4], acc[i][5], acc[i][6], acc[i][7]);
        *(float4*)&out[(long)r * HD + tc * 4]      = o0;
        *(float4*)&out[(long)r * HD + 64 + tc * 4] = o1;
    }
}

// ---------------------------------------------------------------------------
// K2: masked attention, HEAD-PAIRED (r20). grid (BP, 4), block 128 = 2
// waves; wave w handles head h = 2*blockIdx.y + w with the r0-FROZEN body
// verbatim (per-wave code identical to the 93.4 us kernel). Why pairing
// wins without touching the body: rmask rows are head-INDEPENDENT (both
// waves read identical addresses -> fetched once per block, was twice),
// and an even/odd head pair tiles the same 128-B lines of q/k/v (each
// slice is 64 B) -> L1 line sharing. Wave count unchanged (1600x2=3200,
// 12.5 waves/CU); LDS 16 KB caps 10 blk/CU > 6.25 needed (r3's trap
// avoided because the grid halves too); NO min-wave launch_bounds (r2).
// Guards: WRITE = 25600 KB exact, VGPR ~56-64 (no spill).
// ---------------------------------------------------------------------------
__global__ __launch_bounds__(128) void attn_kernel(
    const float* __restrict__ qbuf,   // [T][128]
    const float* __restrict__ kbuf,   // [T][128]
    const float* __restrict__ vbuf,   // [T][128]
    const float* __restrict__ rmask,  // [BP*N][M]
    const float* __restrict__ ninf,   // [BP*N]
    float* __restrict__ xcatT) {      // [BP][HD][N] transposed!
    const int bp   = blockIdx.x;
    const int w    = threadIdx.x >> 6;          // 0..1
    const int h    = blockIdx.y * 2 + w;        // wave = head
    const int lane = threadIdx.x & 63;

    __shared__ float kh[2][M][D];     // 16 KB: per-wave k slice

    // stage k (per wave, own half): 512 float4s over 8 iterations
    #pragma unroll
    for (int i = 0; i < 8; ++i) {
        int e = lane + i * 64;        // f4 index 0..511
        int r = e >> 2, c4 = (e & 3) * 4;
        *(float4*)&kh[w][r][c4] =
            *(const float4*)&kbuf[((long)bp * M + r) * HD + h * D + c4];
    }
    __syncthreads();

    const long t0 = (long)bp * N + lane, t1 = t0 + 64;

    // q rows, 1/sqrt(D)=0.25 folded in
    float qr0[16], qr1[16];
    {
        const float4* q0 = (const float4*)&qbuf[t0 * HD + h * D];
        const float4* q1 = (const float4*)&qbuf[t1 * HD + h * D];
        #pragma unroll
        for (int i = 0; i < 4; ++i) {
            float4 a = q0[i], b = q1[i];
            qr0[i*4+0] = a.x*0.25f; qr0[i*4+1] = a.y*0.25f;
            qr0[i*4+2] = a.z*0.25f; qr0[i*4+3] = a.w*0.25f;
            qr1[i*4+0] = b.x*0.25f; qr1[i*4+1] = b.y*0.25f;
            qr1[i*4+2] = b.z*0.25f; qr1[i*4+3] = b.w*0.25f;
        }
    }

    const float* __restrict__ vbase = vbuf + ((long)bp * M) * HD + h * D;
    const float4* rm0 = (const float4*)&rmask[t0 * M];
    const float4* rm1 = (const float4*)&rmask[t1 * M];

    float sum0 = 0.f, sum1 = 0.f;
    float o0[16], o1[16];
    #pragma unroll
    for (int d = 0; d < 16; ++d) { o0[d] = 0.f; o1[d] = 0.f; }

    for (int mb = 0; mb < 32; ++mb) {          // NOT force-unrolled (VGPR!)
        float4 r0 = rm0[mb], r1 = rm1[mb];
        float r0v[4] = {r0.x, r0.y, r0.z, r0.w};
        float r1v[4] = {r1.x, r1.y, r1.z, r1.w};
        #pragma unroll
        for (int j = 0; j < 4; ++j) {
            const int m = mb * 4 + j;
            const float4* k4 = (const float4*)&kh[w][m][0];
            const float4* v4 = (const float4*)&vbase[(long)m * HD];  // wave-uniform
            float s0 = 0.f, s1 = 0.f;
            #pragma unroll
            for (int q4 = 0; q4 < 4; ++q4) {
                float4 kq = k4[q4];
                s0 += qr0[q4*4+0]*kq.x + qr0[q4*4+1]*kq.y
                    + qr0[q4*4+2]*kq.z + qr0[q4*4+3]*kq.w;
                s1 += qr1[q4*4+0]*kq.x + qr1[q4*4+1]*kq.y
                    + qr1[q4*4+2]*kq.z + qr1[q4*4+3]*kq.w;
            }
            float e0 = __expf(s0 + r0v[j]);
            float e1 = __expf(s1 + r1v[j]);
            sum0 += e0; sum1 += e1;
            #pragma unroll
            for (int q4 = 0; q4 < 4; ++q4) {
                float4 vq = v4[q4];
                o0[q4*4+0] += e0*vq.x; o0[q4*4+1] += e0*vq.y;
                o0[q4*4+2] += e0*vq.z; o0[q4*4+3] += e0*vq.w;
                o1[q4*4+0] += e1*vq.x; o1[q4*4+1] += e1*vq.y;
                o1[q4*4+2] += e1*vq.z; o1[q4*4+3] += e1*vq.w;
            }
        }
    }

    const float inv0 = ((ninf[t0] == 0.f) ? 1.f : 0.f) / sum0;
    const float inv1 = ((ninf[t1] == 0.f) ? 1.f : 0.f) / sum1;
    // transposed, lane-coalesced stores: xcatT[bp][h*16+d][n]
    float* __restrict__ xb = xcatT + (long)bp * HD * N + (long)h * D * N;
    #pragma unroll
    for (int d = 0; d < 16; ++d) {
        xb[d * N + lane]      = o0[d] * inv0;
        xb[d * N + lane + 64] = o1[d] * inv1;
    }
}

// ---------------------------------------------------------------------------
// K3: MoE gating (top-2) + collapsed expert scoring + final softmax.
// grid BP, block 128 (thread = token n). r6-EXACT version (xreg variant
// regressed -12 us in r8 -> reverted): coalesced xcatT reads, two passes,
// f-ascending order, fused loss via last-block ticket.
// ---------------------------------------------------------------------------
__global__ __launch_bounds__(128) void moe_final_kernel(
    const float* __restrict__ xcatT,  // [BP][HD][N]
    const float* __restrict__ Wg,
    const float* __restrict__ ninf, const float* __restrict__ Wep,
    const float* __restrict__ bpv, float* __restrict__ importance,
    unsigned* __restrict__ ticket, float* __restrict__ out) {
    __shared__ float WgS[EMB][NE];   // 4 KB
    __shared__ float WeS[NE][132];   // padded
    __shared__ float red[N];
    __shared__ float impS[NE];

    const int bp = blockIdx.x;
    const int n  = threadIdx.x;

    #pragma unroll
    for (int i = 0; i < 2; ++i) {
        int e = n + i * 128;
        int r = e >> 1, c4 = (e & 1) * 4;
        *(float4*)&WgS[r][c4] = *(const float4*)&Wg[(long)r * NE + c4];
    }
    #pragma unroll
    for (int i = 0; i < 2; ++i) {
        int idx = n + i * 128;
        int r = idx >> 5, c = (idx & 31) * 4;
        *(float4*)&WeS[r][c] = *(const float4*)&Wep[(long)r * HD + c];
    }
    if (n < NE) impS[n] = 0.f;
    __syncthreads();

    const long t = (long)bp * N + n;
    const float* __restrict__ xrow = xcatT + (long)bp * HD * N;  // [f][n]

    float gl[NE];
    #pragma unroll
    for (int e = 0; e < NE; ++e) gl[e] = 0.f;
    for (int f = 0; f < HD; ++f) {           // f ascending: same sum order
        float xv = xrow[f * N + n];          // coalesced across n
        #pragma unroll
        for (int e = 0; e < NE; ++e) gl[e] += xv * WgS[f][e];
    }

    int e0 = 0; float v0 = gl[0];
    #pragma unroll
    for (int e = 1; e < NE; ++e) if (gl[e] > v0) { v0 = gl[e]; e0 = e; }
    int e1 = -1; float v1 = -3.4e38f;
    #pragma unroll
    for (int e = 0; e < NE; ++e) if (e != e0 && gl[e] > v1) { v1 = gl[e]; e1 = e; }
    float ex = __expf(v1 - v0);
    float g0 = 1.f / (1.f + ex);
    float g1 = ex / (1.f + ex);

    atomicAdd(&impS[e0], g0);
    atomicAdd(&impS[e1], g1);

    float s = g0 * bpv[e0] + g1 * bpv[e1];
    for (int f = 0; f < HD; ++f) {           // f ascending: same sum order
        float xv = xrow[f * N + n];          // coalesced, L2-hot
        s += xv * (g0 * WeS[e0][f] + g1 * WeS[e1][f]);
    }
    s = 10.f * tanhf(s) + ninf[t];

    red[n] = s;
    __syncthreads();
    for (int off = 64; off > 0; off >>= 1) {
        if (n < off) red[n] = fmaxf(red[n], red[n + off]);
        __syncthreads();
    }
    float mx = red[0];
    __syncthreads();
    float e = __expf(s - mx);
    red[n] = e;
    __syncthreads();
    for (int off = 64; off > 0; off >>= 1) {
        if (n < off) red[n] += red[n + off];
        __syncthreads();
    }
    float sum = red[0];

    out[t] = e / sum;

    if (n < NE) atomicAdd(&importance[n], impS[n]);

    // ---- fused moe_loss: last block to finish computes it ----
    __syncthreads();                 // drains this block's importance atomics
    if (n == 0) {
        __threadfence();
        unsigned tk = atomicAdd(ticket, 1u);
        if (tk == BP - 1) {          // all 400 blocks' atomics are visible
            __threadfence();
            float imp[NE];
            #pragma unroll
            for (int ei = 0; ei < NE; ++ei)
                imp[ei] = atomicAdd(&importance[ei], 0.f);  // coherent read
            float mean = 0.f;
            #pragma unroll
            for (int ei = 0; ei < NE; ++ei) mean += imp[ei];
            mean *= (1.f / NE);
            float var = 0.f;
            #pragma unroll
            for (int ei = 0; ei < NE; ++ei) {
                float d = imp[ei] - mean;
                var += d * d;
            }
            var *= (1.f / NE);
            out[T] = var / (mean * mean + 1e-10f);
        }
    }
}

// ---------------------------------------------------------------------------
extern "C" void kernel_launch(void* const* d_in, const int* in_sizes, int n_in,
                              void* d_out, int out_size, void* d_ws, size_t ws_size,
                              hipStream_t stream) {
    const float* nodes  = (const float*)d_in[0];
    const float* routes = (const float*)d_in[1];
    const float* ninf   = (const float*)d_in[2];
    const float* rmask  = (const float*)d_in[3];
    const float* Wq     = (const float*)d_in[4];
    const float* Wk     = (const float*)d_in[5];
    const float* Wv     = (const float*)d_in[6];
    const float* Wg     = (const float*)d_in[7];
    const float* We     = (const float*)d_in[8];
    const float* be     = (const float*)d_in[9];
    const float* Wfin   = (const float*)d_in[10];

    float* ws = (float*)d_ws;
    float* Wep        = ws + 16;
    float* bpv        = ws + 1040;
    float* importance = ws + 1048;
    unsigned* ticket  = (unsigned*)(ws + 1056);
    float* qbuf       = ws + 4096;
    float* kbuf       = qbuf + (long)T * HD;
    float* vbuf       = kbuf + (long)T * HD;
    float* xcatT      = vbuf + (long)T * HD;   // [BP][HD][N]

    float* out = (float*)d_out;

    proj_kernel<<<dim3(400, 4), 256, 0, stream>>>(nodes, routes, Wq, Wk, Wv,
                                                  qbuf, kbuf, vbuf,
                                                  We, be, Wfin, Wep, bpv,
                                                  importance, ticket);
    attn_kernel<<<dim3(BP, 4), 128, 0, stream>>>(qbuf, kbuf, vbuf,
                                                 rmask, ninf, xcatT);
    moe_final_kernel<<<BP, 128, 0, stream>>>(xcatT, Wg, ninf, Wep, bpv,
                                             importance, ticket, out);
}

// Round 11
// 281.219 us; speedup vs baseline: 1.3906x; 1.2565x over previous
//
#include <hip/hip_runtime.h>

constexpr int B  = 8,  P = 50, N = 128, M = 128;
constexpr int EMB = 128, H = 8, D = 16;
constexpr int NE = 8;
constexpr int HD = H * D;        // 128
constexpr int E1 = EMB + 1;      // 129
constexpr int BP = B * P;        // 400
constexpr int T  = BP * N;       // 51200 tokens

// ---------------------------------------------------------------------------
// K1: q/k/v projections (r7-proven) + FOLDED prep at blockIdx.y==3.
// grid (400, 4), block 256.
// ---------------------------------------------------------------------------
__global__ __launch_bounds__(256) void proj_kernel(
    const float* __restrict__ nodes,  // [T][128]
    const float* __restrict__ routes, // [T][129]
    const float* __restrict__ Wq, const float* __restrict__ Wk,
    const float* __restrict__ Wv,
    float* __restrict__ qo, float* __restrict__ ko, float* __restrict__ vo,
    const float* __restrict__ We, const float* __restrict__ be,
    const float* __restrict__ Wf,
    float* __restrict__ Wep, float* __restrict__ bpv,
    float* __restrict__ importance, unsigned* __restrict__ ticket) {
    const int mat = blockIdx.y;

    if (mat == 3) {                   // ---- folded prep ----
        const int e = blockIdx.x;
        if (e >= NE) return;
        const int f = threadIdx.x;
        if (f < HD) {
            float a = 0.f;
            const long base = ((long)e * HD + f) * E1;
            for (int o = 0; o < E1; ++o) a += We[base + o] * Wf[o];
            Wep[e * HD + f] = a;
        } else if (f == HD) {
            float b = 0.f;
            for (int o = 0; o < E1; ++o) b += be[(long)e * E1 + o] * Wf[o];
            bpv[e] = b;
        }
        if (e == 0) {
            if (f >= 140 && f < 140 + NE) importance[f - 140] = 0.f;
            if (f == 150) *ticket = 0u;
        }
        return;
    }

    const float* __restrict__ X = (mat == 0) ? nodes : routes;
    const float* __restrict__ W = (mat == 0) ? Wq : (mat == 1 ? Wk : Wv);
    float* __restrict__ out     = (mat == 0) ? qo : (mat == 1 ? ko : vo);
    const int Kd = (mat == 0) ? EMB : E1;
    const int nit = (Kd + 7) >> 3;

    const int row0 = blockIdx.x * 128;
    const int tid  = threadIdx.x;
    const int tr   = tid >> 4;        // 0..15
    const int tc   = tid & 15;        // 0..15

    __shared__ float XT[2][8][132];   // [buf][k][row], padded
    __shared__ float WS[2][8][132];   // [buf][k][col]

    float acc[8][8];
    #pragma unroll
    for (int i = 0; i < 8; ++i)
        #pragma unroll
        for (int j = 0; j < 8; ++j) acc[i][j] = 0.f;

    float xr[4];
    float4 wr;
    const int xkx = tid & 7, xrr = tid >> 3;          // +i*32 rows
    const int wkx = tid >> 5, wc4 = (tid & 31) * 4;

    {   // prologue: fetch tile 0
        #pragma unroll
        for (int i = 0; i < 4; ++i) {
            int kg = xkx;
            xr[i] = (kg < Kd) ? X[(long)(row0 + xrr + i * 32) * Kd + kg] : 0.f;
        }
        wr = (wkx < Kd) ? *(const float4*)&W[(long)wkx * HD + wc4]
                        : make_float4(0.f, 0.f, 0.f, 0.f);
        #pragma unroll
        for (int i = 0; i < 4; ++i) XT[0][xkx][xrr + i * 32] = xr[i];
        *(float4*)&WS[0][wkx][wc4] = wr;
    }
    __syncthreads();

    for (int it = 0; it < nit; ++it) {
        const int buf = it & 1;
        if (it + 1 < nit) {
            const int kk = (it + 1) * 8;
            #pragma unroll
            for (int i = 0; i < 4; ++i) {
                int kg = kk + xkx;
                xr[i] = (kg < Kd) ? X[(long)(row0 + xrr + i * 32) * Kd + kg] : 0.f;
            }
            int kg = kk + wkx;
            wr = (kg < Kd) ? *(const float4*)&W[(long)kg * HD + wc4]
                           : make_float4(0.f, 0.f, 0.f, 0.f);
        }

        #pragma unroll
        for (int k = 0; k < 8; ++k) {
            float4 xa = *(const float4*)&XT[buf][k][tr * 4];
            float4 xb = *(const float4*)&XT[buf][k][64 + tr * 4];
            float4 wa = *(const float4*)&WS[buf][k][tc * 4];
            float4 wb = *(const float4*)&WS[buf][k][64 + tc * 4];
            float xv[8] = {xa.x, xa.y, xa.z, xa.w, xb.x, xb.y, xb.z, xb.w};
            float wvv[8] = {wa.x, wa.y, wa.z, wa.w, wb.x, wb.y, wb.z, wb.w};
            #pragma unroll
            for (int i = 0; i < 8; ++i)
                #pragma unroll
                for (int j = 0; j < 8; ++j) acc[i][j] += xv[i] * wvv[j];
        }

        if (it + 1 < nit) {
            const int nb = buf ^ 1;
            #pragma unroll
            for (int i = 0; i < 4; ++i) XT[nb][xkx][xrr + i * 32] = xr[i];
            *(float4*)&WS[nb][wkx][wc4] = wr;
        }
        __syncthreads();
    }

    #pragma unroll
    for (int i = 0; i < 8; ++i) {
        int r = row0 + (i < 4 ? 0 : 64) + tr * 4 + (i & 3);
        float4 o0 = make_float4(acc[i][0], acc[i][1], acc[i][2], acc[i][3]);
        float4 o1 = make_float4(acc[i][4], acc[i][5], acc[i][6], acc[i][7]);
        *(float4*)&out[(long)r * HD + tc * 4]      = o0;
        *(float4*)&out[(long)r * HD + 64 + tc * 4] = o1;
    }
}

// ---------------------------------------------------------------------------
// K2: masked attention per (bp, head). grid (BP, 8), block 64 (1 wave).
// r6-EXACT (93.4-93.9 us proven). The r0 body is FROZEN — 9 variants lost:
// more waves (r1), head-merge (r2), LDS-v (r3), M-split (r4), prefetch
// (r5), chunk-stage (r7), moe-tail fusion (r9), head-pairing (r10).
// r10's lesson: h MUST stay blockIdx-derived — the per-m v loads compile
// to SCALAR (s_load) only when vbase is provably wave-uniform; moving h
// into thread-space demotes them to vector loads and doubles the time.
// Epilogue stores xcat transposed (lane-coalesced) for moe.
// ---------------------------------------------------------------------------
__global__ __launch_bounds__(64) void attn_kernel(
    const float* __restrict__ qbuf,   // [T][128]
    const float* __restrict__ kbuf,   // [T][128]
    const float* __restrict__ vbuf,   // [T][128]
    const float* __restrict__ rmask,  // [BP*N][M]
    const float* __restrict__ ninf,   // [BP*N]
    float* __restrict__ xcatT) {      // [BP][HD][N] transposed!
    const int bp  = blockIdx.x;
    const int h   = blockIdx.y;       // MUST be blockIdx-derived (r10!)
    const int tid = threadIdx.x;

    __shared__ float kh[M][D];        // 8 KB (k only)

    // stage k: 512 float4s over 8 iterations (fills ALL 128 rows)
    #pragma unroll
    for (int i = 0; i < 8; ++i) {
        int e = tid + i * 64;         // f4 index 0..511
        int r = e >> 2, c4 = (e & 3) * 4;
        *(float4*)&kh[r][c4] = *(const float4*)&kbuf[((long)bp * M + r) * HD + h * D + c4];
    }
    __syncthreads();

    const long t0 = (long)bp * N + tid, t1 = t0 + 64;

    // q rows, 1/sqrt(D)=0.25 folded in
    float qr0[16], qr1[16];
    {
        const float4* q0 = (const float4*)&qbuf[t0 * HD + h * D];
        const float4* q1 = (const float4*)&qbuf[t1 * HD + h * D];
        #pragma unroll
        for (int i = 0; i < 4; ++i) {
            float4 a = q0[i], b = q1[i];
            qr0[i*4+0] = a.x*0.25f; qr0[i*4+1] = a.y*0.25f;
            qr0[i*4+2] = a.z*0.25f; qr0[i*4+3] = a.w*0.25f;
            qr1[i*4+0] = b.x*0.25f; qr1[i*4+1] = b.y*0.25f;
            qr1[i*4+2] = b.z*0.25f; qr1[i*4+3] = b.w*0.25f;
        }
    }

    const float* __restrict__ vbase = vbuf + ((long)bp * M) * HD + h * D;
    const float4* rm0 = (const float4*)&rmask[t0 * M];
    const float4* rm1 = (const float4*)&rmask[t1 * M];

    float sum0 = 0.f, sum1 = 0.f;
    float o0[16], o1[16];
    #pragma unroll
    for (int d = 0; d < 16; ++d) { o0[d] = 0.f; o1[d] = 0.f; }

    for (int mb = 0; mb < 32; ++mb) {          // NOT force-unrolled (VGPR!)
        float4 r0 = rm0[mb], r1 = rm1[mb];
        float r0v[4] = {r0.x, r0.y, r0.z, r0.w};
        float r1v[4] = {r1.x, r1.y, r1.z, r1.w};
        #pragma unroll
        for (int j = 0; j < 4; ++j) {
            const int m = mb * 4 + j;
            const float4* k4 = (const float4*)&kh[m][0];
            const float4* v4 = (const float4*)&vbase[(long)m * HD];  // scalar path
            float s0 = 0.f, s1 = 0.f;
            #pragma unroll
            for (int q4 = 0; q4 < 4; ++q4) {
                float4 kq = k4[q4];
                s0 += qr0[q4*4+0]*kq.x + qr0[q4*4+1]*kq.y
                    + qr0[q4*4+2]*kq.z + qr0[q4*4+3]*kq.w;
                s1 += qr1[q4*4+0]*kq.x + qr1[q4*4+1]*kq.y
                    + qr1[q4*4+2]*kq.z + qr1[q4*4+3]*kq.w;
            }
            float e0 = __expf(s0 + r0v[j]);
            float e1 = __expf(s1 + r1v[j]);
            sum0 += e0; sum1 += e1;
            #pragma unroll
            for (int q4 = 0; q4 < 4; ++q4) {
                float4 vq = v4[q4];
                o0[q4*4+0] += e0*vq.x; o0[q4*4+1] += e0*vq.y;
                o0[q4*4+2] += e0*vq.z; o0[q4*4+3] += e0*vq.w;
                o1[q4*4+0] += e1*vq.x; o1[q4*4+1] += e1*vq.y;
                o1[q4*4+2] += e1*vq.z; o1[q4*4+3] += e1*vq.w;
            }
        }
    }

    const float inv0 = ((ninf[t0] == 0.f) ? 1.f : 0.f) / sum0;
    const float inv1 = ((ninf[t1] == 0.f) ? 1.f : 0.f) / sum1;
    // transposed, lane-coalesced stores: xcatT[bp][h*16+d][n]
    float* __restrict__ xb = xcatT + (long)bp * HD * N + (long)h * D * N;
    #pragma unroll
    for (int d = 0; d < 16; ++d) {
        xb[d * N + tid]      = o0[d] * inv0;
        xb[d * N + tid + 64] = o1[d] * inv1;
    }
}

// ---------------------------------------------------------------------------
// K3: MoE gating (top-2) + collapsed expert scoring + final softmax.
// grid BP, block 128 (thread = token n). r6-EXACT version (xreg variant
// regressed -12 us in r8): coalesced xcatT reads, two passes, f-ascending
// order, fused loss via last-block ticket.
// ---------------------------------------------------------------------------
__global__ __launch_bounds__(128) void moe_final_kernel(
    const float* __restrict__ xcatT,  // [BP][HD][N]
    const float* __restrict__ Wg,
    const float* __restrict__ ninf, const float* __restrict__ Wep,
    const float* __restrict__ bpv, float* __restrict__ importance,
    unsigned* __restrict__ ticket, float* __restrict__ out) {
    __shared__ float WgS[EMB][NE];   // 4 KB
    __shared__ float WeS[NE][132];   // padded
    __shared__ float red[N];
    __shared__ float impS[NE];

    const int bp = blockIdx.x;
    const int n  = threadIdx.x;

    #pragma unroll
    for (int i = 0; i < 2; ++i) {
        int e = n + i * 128;
        int r = e >> 1, c4 = (e & 1) * 4;
        *(float4*)&WgS[r][c4] = *(const float4*)&Wg[(long)r * NE + c4];
    }
    #pragma unroll
    for (int i = 0; i < 2; ++i) {
        int idx = n + i * 128;
        int r = idx >> 5, c = (idx & 31) * 4;
        *(float4*)&WeS[r][c] = *(const float4*)&Wep[(long)r * HD + c];
    }
    if (n < NE) impS[n] = 0.f;
    __syncthreads();

    const long t = (long)bp * N + n;
    const float* __restrict__ xrow = xcatT + (long)bp * HD * N;  // [f][n]

    float gl[NE];
    #pragma unroll
    for (int e = 0; e < NE; ++e) gl[e] = 0.f;
    for (int f = 0; f < HD; ++f) {           // f ascending: same sum order
        float xv = xrow[f * N + n];          // coalesced across n
        #pragma unroll
        for (int e = 0; e < NE; ++e) gl[e] += xv * WgS[f][e];
    }

    int e0 = 0; float v0 = gl[0];
    #pragma unroll
    for (int e = 1; e < NE; ++e) if (gl[e] > v0) { v0 = gl[e]; e0 = e; }
    int e1 = -1; float v1 = -3.4e38f;
    #pragma unroll
    for (int e = 0; e < NE; ++e) if (e != e0 && gl[e] > v1) { v1 = gl[e]; e1 = e; }
    float ex = __expf(v1 - v0);
    float g0 = 1.f / (1.f + ex);
    float g1 = ex / (1.f + ex);

    atomicAdd(&impS[e0], g0);
    atomicAdd(&impS[e1], g1);

    float s = g0 * bpv[e0] + g1 * bpv[e1];
    for (int f = 0; f < HD; ++f) {           // f ascending: same sum order
        float xv = xrow[f * N + n];          // coalesced, L2-hot
        s += xv * (g0 * WeS[e0][f] + g1 * WeS[e1][f]);
    }
    s = 10.f * tanhf(s) + ninf[t];

    red[n] = s;
    __syncthreads();
    for (int off = 64; off > 0; off >>= 1) {
        if (n < off) red[n] = fmaxf(red[n], red[n + off]);
        __syncthreads();
    }
    float mx = red[0];
    __syncthreads();
    float e = __expf(s - mx);
    red[n] = e;
    __syncthreads();
    for (int off = 64; off > 0; off >>= 1) {
        if (n < off) red[n] += red[n + off];
        __syncthreads();
    }
    float sum = red[0];

    out[t] = e / sum;

    if (n < NE) atomicAdd(&importance[n], impS[n]);

    // ---- fused moe_loss: last block to finish computes it ----
    __syncthreads();                 // drains this block's importance atomics
    if (n == 0) {
        __threadfence();
        unsigned tk = atomicAdd(ticket, 1u);
        if (tk == BP - 1) {          // all 400 blocks' atomics are visible
            __threadfence();
            float imp[NE];
            #pragma unroll
            for (int ei = 0; ei < NE; ++ei)
                imp[ei] = atomicAdd(&importance[ei], 0.f);  // coherent read
            float mean = 0.f;
            #pragma unroll
            for (int ei = 0; ei < NE; ++ei) mean += imp[ei];
            mean *= (1.f / NE);
            float var = 0.f;
            #pragma unroll
            for (int ei = 0; ei < NE; ++ei) {
                float d = imp[ei] - mean;
                var += d * d;
            }
            var *= (1.f / NE);
            out[T] = var / (mean * mean + 1e-10f);
        }
    }
}

// ---------------------------------------------------------------------------
extern "C" void kernel_launch(void* const* d_in, const int* in_sizes, int n_in,
                              void* d_out, int out_size, void* d_ws, size_t ws_size,
                              hipStream_t stream) {
    const float* nodes  = (const float*)d_in[0];
    const float* routes = (const float*)d_in[1];
    const float* ninf   = (const float*)d_in[2];
    const float* rmask  = (const float*)d_in[3];
    const float* Wq     = (const float*)d_in[4];
    const float* Wk     = (const float*)d_in[5];
    const float* Wv     = (const float*)d_in[6];
    const float* Wg     = (const float*)d_in[7];
    const float* We     = (const float*)d_in[8];
    const float* be     = (const float*)d_in[9];
    const float* Wfin   = (const float*)d_in[10];

    float* ws = (float*)d_ws;
    float* Wep        = ws + 16;
    float* bpv        = ws + 1040;
    float* importance = ws + 1048;
    unsigned* ticket  = (unsigned*)(ws + 1056);
    float* qbuf       = ws + 4096;
    float* kbuf       = qbuf + (long)T * HD;
    float* vbuf       = kbuf + (long)T * HD;
    float* xcatT      = vbuf + (long)T * HD;   // [BP][HD][N]

    float* out = (float*)d_out;

    proj_kernel<<<dim3(400, 4), 256, 0, stream>>>(nodes, routes, Wq, Wk, Wv,
                                                  qbuf, kbuf, vbuf,
                                                  We, be, Wfin, Wep, bpv,
                                                  importance, ticket);
    attn_kernel<<<dim3(BP, H), 64, 0, stream>>>(qbuf, kbuf, vbuf,
                                                rmask, ninf, xcatT);
    moe_final_kernel<<<BP, 128, 0, stream>>>(xcatT, Wg, ninf, Wep, bpv,
                                             importance, ticket, out);
}